// Round 12
// baseline (812.257 us; speedup 1.0000x reference)
//
#include <hip/hip_runtime.h>

#define BB 64
#define SS 2048
#define DD 128
#define HH 128

typedef float v2f __attribute__((ext_vector_type(2)));

// VOP3P packed-f32 FMA, all operands VGPR PAIRS.
// PKBLO: both result lanes use LOW word of src0:  acc += h.lo * (w.lo, w.hi)
#define PKBLO(acc, hp, w) \
    asm("v_pk_fma_f32 %0, %1, %2, %0 op_sel_hi:[0,1,1]" \
        : "+v"(acc) : "v"(hp), "v"(w))
// PKBHI: both result lanes use HIGH word of src0
#define PKBHI(acc, hp, w) \
    asm("v_pk_fma_f32 %0, %1, %2, %0 op_sel:[1,0,0] op_sel_hi:[1,1,1]" \
        : "+v"(acc) : "v"(hp), "v"(w))

// Unsinkable loads of Wh column-pairs (j0,j0+1) and (j0+2,j0+3) at one k.
#define LDA(r, u) asm volatile("global_load_dwordx2 %0, %1, off" \
    : "=&v"(a##r##u) : "v"(Whp + (long)(32 * s + kr##r * 4 + (u)) * HH + j0));
#define LDB(r, u) asm volatile("global_load_dwordx2 %0, %1, off" \
    : "=&v"(b##r##u) : "v"(Whp + (long)(32 * s + kr##r * 4 + (u)) * HH + j0 + 2));

__device__ __forceinline__ float fast_tanh(float x) {
    // tanh(x) = 1 - 2/(e^{2x}+1); exact at +-inf, ~1e-6 rel err
    float e = __expf(2.0f * x);
    return 1.0f - __fdividef(2.0f, e + 1.0f);
}

// quad-local butterfly ALLreduce (lanes 4g..4g+3) via DPP quad_perm — VALU only
__device__ __forceinline__ float quad_allreduce(float v) {
    int a = __builtin_amdgcn_update_dpp(0, __float_as_int(v), 0xB1, 0xF, 0xF, true); // xor1
    v += __int_as_float(a);
    int c = __builtin_amdgcn_update_dpp(0, __float_as_int(v), 0x4E, 0xF, 0xF, true); // xor2
    v += __int_as_float(c);
    return v;
}

// LDS-only workgroup barrier: NO vmcnt drain (global ops stay in flight).
__device__ __forceinline__ void wg_sync_lds() {
    asm volatile("s_waitcnt lgkmcnt(0)\n\ts_barrier" ::: "memory");
}

// ---------------------------------------------------------------------------
// Kernel 1: xproj = x @ Wx + b  (register-tiled fp32 GEMM) — unchanged (~45us)
// ---------------------------------------------------------------------------
__global__ __launch_bounds__(256, 2)
void xproj_kernel(const float* __restrict__ x, const float* __restrict__ W,
                  const float* __restrict__ bias, float* __restrict__ out) {
    __shared__ __align__(16) float4 wxs[64 * 32];   // Wx half: [64 k][128 j]
    __shared__ __align__(16) float4 xsw[128 * 16];  // x half:  [128 r][64 k], swizzled
    const int tid = threadIdx.x;
    const int tx  = tid & 15;
    const int ty  = tid >> 4;
    const long row0 = (long)blockIdx.x * 128;

    float acc[8][8];
#pragma unroll
    for (int i = 0; i < 8; ++i)
#pragma unroll
        for (int j = 0; j < 8; ++j) acc[i][j] = 0.f;

    for (int kh = 0; kh < 2; ++kh) {
        {
            const float4* wg = (const float4*)(W + kh * 64 * HH);
#pragma unroll
            for (int i = 0; i < 8; ++i) wxs[tid + i * 256] = wg[tid + i * 256];
        }
        {
#pragma unroll
            for (int i = 0; i < 8; ++i) {
                const int g  = tid + i * 256;
                const int r  = g >> 4;
                const int k4 = g & 15;
                const float4 v = ((const float4*)(x + (row0 + r) * DD + kh * 64))[k4];
                xsw[r * 16 + (k4 ^ ((r >> 3) & 7))] = v;
            }
        }
        __syncthreads();

        for (int k4 = 0; k4 < 16; ++k4) {
            float4 xa[8];
#pragma unroll
            for (int i = 0; i < 8; ++i)
                xa[i] = xsw[(ty * 8 + i) * 16 + (k4 ^ (ty & 7))];
            float4 wa[4][2];
#pragma unroll
            for (int kk = 0; kk < 4; ++kk) {
                wa[kk][0] = wxs[(k4 * 4 + kk) * 32 + tx * 2];
                wa[kk][1] = wxs[(k4 * 4 + kk) * 32 + tx * 2 + 1];
            }
#pragma unroll
            for (int i = 0; i < 8; ++i) {
#pragma unroll
                for (int kk = 0; kk < 4; ++kk) {
                    const float xv = (kk == 0) ? xa[i].x : (kk == 1) ? xa[i].y
                                   : (kk == 2) ? xa[i].z : xa[i].w;
                    acc[i][0] = fmaf(xv, wa[kk][0].x, acc[i][0]);
                    acc[i][1] = fmaf(xv, wa[kk][0].y, acc[i][1]);
                    acc[i][2] = fmaf(xv, wa[kk][0].z, acc[i][2]);
                    acc[i][3] = fmaf(xv, wa[kk][0].w, acc[i][3]);
                    acc[i][4] = fmaf(xv, wa[kk][1].x, acc[i][4]);
                    acc[i][5] = fmaf(xv, wa[kk][1].y, acc[i][5]);
                    acc[i][6] = fmaf(xv, wa[kk][1].z, acc[i][6]);
                    acc[i][7] = fmaf(xv, wa[kk][1].w, acc[i][7]);
                }
            }
        }
        __syncthreads();
    }

    const float4 b0 = ((const float4*)bias)[tx * 2];
    const float4 b1 = ((const float4*)bias)[tx * 2 + 1];
#pragma unroll
    for (int i = 0; i < 8; ++i) {
        const float4 o0 = make_float4(acc[i][0] + b0.x, acc[i][1] + b0.y,
                                      acc[i][2] + b0.z, acc[i][3] + b0.w);
        const float4 o1 = make_float4(acc[i][4] + b1.x, acc[i][5] + b1.y,
                                      acc[i][6] + b1.z, acc[i][7] + b1.w);
        float4* og = (float4*)(out + (row0 + ty * 8 + i) * HH);
        og[tx * 2]     = o0;
        og[tx * 2 + 1] = o1;
    }
}

// ---------------------------------------------------------------------------
// Kernel 2: recurrence v9 — 64 blocks x 128 threads (2 waves), J=4 cols/lane,
// k-split 4. Attacks the measured floor (LDS pipe ~12-13 cyc/DS-instr,
// CU-serialized): DS instrs/step 40 -> 18.
//  - amdgpu_waves_per_eu(1,1): occupancy target 1 wave/EU -> allocator gets
//    the full 256-VGPR budget (R10 proved the heuristic caps at ~60 without)
//  - Wh = 64 v2f via unsinkable volatile global_load_dwordx2
//  - per step: 8 staggered ds_read_b128 + 1 ds_write_b32/wave (col = tid,
//    consecutive -> conflict-free) + 1 coalesced global_store/wave
//  - 2-wave lgkm-only barrier; xproj scalar/step, prefetched 2 chunks ahead
// ---------------------------------------------------------------------------
__global__ __launch_bounds__(128, 1) __attribute__((amdgpu_waves_per_eu(1, 1)))
void rnn_kernel(const float* __restrict__ W, float* __restrict__ out) {
    const int CH = 16;
    const int NC = SS / CH;   // 128

    __shared__ __align__(16) float hb[2][HH];      // double-buffered state (1KB)

    const int b   = blockIdx.x;
    const int tid = threadIdx.x;     // 0..127; writes col = tid
    const int w   = tid >> 6;
    const int l   = tid & 63;
    const int s   = l & 3;           // k-slice: k in [32s, 32s+32)
    const int j0  = 64 * w + 4 * (l >> 2);   // col group (j0 .. j0+3)

    // staggered k-groups: 4 slices read float4-indices distinct mod 8 -> 0 conflicts
    const int kr0 = (0 + 2 * s) & 7, kr1 = (1 + 2 * s) & 7;
    const int kr2 = (2 + 2 * s) & 7, kr3 = (3 + 2 * s) & 7;
    const int kr4 = (4 + 2 * s) & 7, kr5 = (5 + 2 * s) & 7;
    const int kr6 = (6 + 2 * s) & 7, kr7 = (7 + 2 * s) & 7;
    const int ix0 = 8 * s + kr0, ix1 = 8 * s + kr1, ix2 = 8 * s + kr2,
              ix3 = 8 * s + kr3, ix4 = 8 * s + kr4, ix5 = 8 * s + kr5,
              ix6 = 8 * s + kr6, ix7 = 8 * s + kr7;

    const float* Whp = W + (long)DD * HH;

    // 64 v2f = 128 VGPRs of Wh (4 cols x 32 k), loaded via opaque asm
    v2f a00,a01,a02,a03, a10,a11,a12,a13, a20,a21,a22,a23, a30,a31,a32,a33;
    v2f a40,a41,a42,a43, a50,a51,a52,a53, a60,a61,a62,a63, a70,a71,a72,a73;
    v2f b00,b01,b02,b03, b10,b11,b12,b13, b20,b21,b22,b23, b30,b31,b32,b33;
    v2f b40,b41,b42,b43, b50,b51,b52,b53, b60,b61,b62,b63, b70,b71,b72,b73;
    LDA(0,0) LDA(0,1) LDA(0,2) LDA(0,3)  LDB(0,0) LDB(0,1) LDB(0,2) LDB(0,3)
    LDA(1,0) LDA(1,1) LDA(1,2) LDA(1,3)  LDB(1,0) LDB(1,1) LDB(1,2) LDB(1,3)
    LDA(2,0) LDA(2,1) LDA(2,2) LDA(2,3)  LDB(2,0) LDB(2,1) LDB(2,2) LDB(2,3)
    LDA(3,0) LDA(3,1) LDA(3,2) LDA(3,3)  LDB(3,0) LDB(3,1) LDB(3,2) LDB(3,3)
    LDA(4,0) LDA(4,1) LDA(4,2) LDA(4,3)  LDB(4,0) LDB(4,1) LDB(4,2) LDB(4,3)
    LDA(5,0) LDA(5,1) LDA(5,2) LDA(5,3)  LDB(5,0) LDB(5,1) LDB(5,2) LDB(5,3)
    LDA(6,0) LDA(6,1) LDA(6,2) LDA(6,3)  LDB(6,0) LDB(6,1) LDB(6,2) LDB(6,3)
    LDA(7,0) LDA(7,1) LDA(7,2) LDA(7,3)  LDB(7,0) LDB(7,1) LDB(7,2) LDB(7,3)

    float* const xbase = out + (long)b * SS * HH;

    hb[0][tid] = 0.f;
    hb[1][tid] = 0.f;

    // xproj for this lane's output col (= tid), 16 steps/chunk, 2 chunks deep
    float xpc[16], nxt[16];
#pragma unroll
    for (int i = 0; i < 16; ++i) xpc[i] = xbase[(long)i * HH + tid];
#pragma unroll
    for (int i = 0; i < 16; ++i) nxt[i] = xbase[(long)(CH + i) * HH + tid];

    // all Wh (asm loads -> manual wait) + xpc in flight -> drain, then sync
    asm volatile("s_waitcnt vmcnt(0)" ::: "memory");
    wg_sync_lds();

    for (int c = 0; c < NC; ++c) {
#pragma unroll
        for (int tt = 0; tt < CH; ++tt) {
            const int t = c * CH + tt;
            const float4* hv = (const float4*)hb[(t + 1) & 1];

            v2f p0 = {0.f,0.f}, p1 = {0.f,0.f}, p2 = {0.f,0.f}, p3 = {0.f,0.f};
            v2f q0 = {0.f,0.f}, q1 = {0.f,0.f}, q2 = {0.f,0.f}, q3 = {0.f,0.f};
#define STEP_R(r) { \
            const float4 h4 = hv[ix##r]; \
            v2f hlo; hlo.x = h4.x; hlo.y = h4.y; \
            v2f hhi; hhi.x = h4.z; hhi.y = h4.w; \
            PKBLO(p0, hlo, a##r##0); PKBLO(q0, hlo, b##r##0); \
            PKBHI(p1, hlo, a##r##1); PKBHI(q1, hlo, b##r##1); \
            PKBLO(p2, hhi, a##r##2); PKBLO(q2, hhi, b##r##2); \
            PKBHI(p3, hhi, a##r##3); PKBHI(q3, hhi, b##r##3); }
            STEP_R(0) STEP_R(1) STEP_R(2) STEP_R(3)
            STEP_R(4) STEP_R(5) STEP_R(6) STEP_R(7)
#undef STEP_R
            const v2f P = (p0 + p1) + (p2 + p3);   // (col j0,   col j0+1)
            const v2f Q = (q0 + q1) + (q2 + q3);   // (col j0+2, col j0+3)

            const float rpx = quad_allreduce(P.x);
            const float rpy = quad_allreduce(P.y);
            const float rqx = quad_allreduce(Q.x);
            const float rqy = quad_allreduce(Q.y);

            const float e0 = (s & 1) ? rpy : rpx;
            const float e1 = (s & 1) ? rqy : rqx;
            const float hx = ((s & 2) ? e1 : e0) + xpc[tt];
            const float h  = fast_tanh(hx);

            hb[t & 1][tid] = h;                    // state: 1 ds_write/wave
            xbase[(long)t * HH + tid] = h;         // output: coalesced, never waited
            wg_sync_lds();                         // 2-wave, lgkm-only
        }
        // rotate prefetch: xpc <- nxt, nxt <- chunk c+2 (16-step margin)
        if (c + 1 < NC) {
#pragma unroll
            for (int i = 0; i < 16; ++i) xpc[i] = nxt[i];
            if (c + 2 < NC) {
                const float* g = xbase + (long)(c + 2) * CH * HH + tid;
#pragma unroll
                for (int i = 0; i < 16; ++i) nxt[i] = g[(long)i * HH];
            }
        }
    }

    // final hidden state: lane holds its col's last h? recompute from hb
    out[(long)BB * SS * HH + b * HH + tid] = hb[(SS - 1) & 1][tid];
}

extern "C" void kernel_launch(void* const* d_in, const int* in_sizes, int n_in,
                              void* d_out, int out_size, void* d_ws, size_t ws_size,
                              hipStream_t stream) {
    const float* x    = (const float*)d_in[0];
    const float* W    = (const float*)d_in[1];
    const float* bias = (const float*)d_in[2];
    float* out = (float*)d_out;

    xproj_kernel<<<dim3((BB * SS) / 128), dim3(256), 0, stream>>>(x, W, bias, out);
    rnn_kernel<<<dim3(BB), dim3(128), 0, stream>>>(W, out);
}